// Round 1
// 396.234 us; speedup vs baseline: 1.0084x; 1.0084x over previous
//
#include <hip/hip_runtime.h>
#include <hip/hip_bf16.h>

#define S_SAMPLES 4096
#define NAG 16

typedef __attribute__((ext_vector_type(8))) short short8;   // 8 bf16 = 4 VGPRs (MFMA A/B frag)
typedef __attribute__((ext_vector_type(4))) float f32x4;    // MFMA C/D frag

union F8 { short8 v; unsigned u[4]; };

__device__ __forceinline__ float tanh_fast(float x) {
    float ax = fabsf(x);
    float e  = __expf(-2.0f * ax);
    float t  = (1.0f - e) * __builtin_amdgcn_rcpf(1.0f + e);
    return copysignf(t, x);
}

__device__ __forceinline__ unsigned pk2(float a, float b) {
    float2 f; f.x = a; f.y = b;
    __hip_bfloat162 h = __float22bfloat162_rn(f);
    unsigned r; __builtin_memcpy(&r, &h, 4); return r;
}

__device__ __forceinline__ short bfs(float a) {
    __hip_bfloat16 h = __float2bfloat16(a);
    short r; __builtin_memcpy(&r, &h, 2); return r;
}

__device__ __forceinline__ float4 ld4(const float* p) {
    return *reinterpret_cast<const float4*>(p);
}

// Row stride for all bf16 LDS tiles: 40 shorts = 80 B (16B-multiple for b128).
#define STR 40

// Wave-local LDS fence. All staging tiles are PER-WAVE private, so a block
// barrier is not needed between stage and consume -- only completion of this
// wave's own DS ops. DS ops from one wave are processed in order by the LDS
// pipe; lgkmcnt(0) guarantees the writes have landed before following reads.
// "memory" clobber stops the compiler reordering LDS accesses across it.
#define LDS_FENCE() asm volatile("s_waitcnt lgkmcnt(0)" ::: "memory")

__global__ __launch_bounds__(256, 2) void att_mask_kernel(
    const float* __restrict__ x, const float* __restrict__ L,
    const float* __restrict__ Aq, const float* __restrict__ Ak,
    const float* __restrict__ Av, const float* __restrict__ Ao,
    float* __restrict__ out)
{
    // Per-wave bf16 scratch (no cross-wave sharing except sRsq)
    __shared__ alignas(16) short sQ [4][32 * STR];  // Q[r][n], n zero-padded 16..31
    __shared__ alignas(16) short sK [4][32 * STR];  // K[s][n], zero-padded
    __shared__ alignas(16) short sVt[4][16 * STR];  // V^T[n][s], s=0..31
    __shared__ alignas(16) short sAt[4][32 * STR];  // attn[r][s]
    __shared__ alignas(16) float sRsq[16 * 17];

    const int tid  = threadIdx.x;
    const int lane = tid & 63;
    const int w    = tid >> 6;
    const int c4   = lane & 15;       // n / col index
    const int q    = lane >> 4;       // quad
    const int s_idx = blockIdx.x;

    short* qw = sQ[w];  short* kw = sK[w];  short* vtw = sVt[w];  short* atw = sAt[w];

    // ---- one-time: A-matrix MFMA A-fragments (reg-resident) ----
    // A_frag[m][rh][kb]: lane holds Amat[r = c4+16rh][d = 32kb + 8q + j], j=0..7
    F8 aF[3][2][2];
    {
        const float* mats[3] = { Aq, Ak, Av };
        #pragma unroll
        for (int m = 0; m < 3; ++m)
            #pragma unroll
            for (int rh = 0; rh < 2; ++rh)
                #pragma unroll
                for (int kb = 0; kb < 2; ++kb) {
                    const float* p = mats[m] + (c4 + 16 * rh) * 64 + 32 * kb + 8 * q;
                    float4 a0 = ld4(p), a1 = ld4(p + 4);
                    aF[m][rh][kb].u[0] = pk2(a0.x, a0.y);
                    aF[m][rh][kb].u[1] = pk2(a0.z, a0.w);
                    aF[m][rh][kb].u[2] = pk2(a1.x, a1.y);
                    aF[m][rh][kb].u[3] = pk2(a1.z, a1.w);
                }
    }
    // Ao values matching the o C-fragment rows r = 4q+reg+16rh
    float4 ao0 = ld4(Ao + 4 * q);
    float4 ao1 = ld4(Ao + 16 + 4 * q);

    // ---- zero-fill Q/K pad columns n=16..31 (read by scores MFMA K-dim) ----
    {
        int r = lane & 31, hh = lane >> 5;
        uint2 z; z.x = 0; z.y = 0;
        *reinterpret_cast<uint2*>(&qw[r * STR + 16 + 8 * hh]) = z;
        *reinterpret_cast<uint2*>(&qw[r * STR + 20 + 8 * hh]) = z;
        *reinterpret_cast<uint2*>(&kw[r * STR + 16 + 8 * hh]) = z;
        *reinterpret_cast<uint2*>(&kw[r * STR + 20 + 8 * hh]) = z;
    }

    const f32x4 zz = {0.f, 0.f, 0.f, 0.f};

    // ---- software pipeline: depth-1 prefetch of x rows + L row ----
    const int b0 = s_idx * NAG + w * 4;
    const float* xb = x + (size_t)b0 * 1024 + 128 * q + c4;  // lane's gather base
    const float* Lb = L + (size_t)b0 * 256 + c4;             // row 0 of L[b]

    float xv[2][16];   // ping-pong x fragments (static index via full unroll)
    float lvb[2];

    #pragma unroll
    for (int kb = 0; kb < 2; ++kb)
        #pragma unroll
        for (int j = 0; j < 8; ++j)
            xv[0][kb * 8 + j] = xb[512 * kb + 16 * j];
    lvb[0] = (lane < 16) ? Lb[0] : 0.0f;

    #pragma unroll
    for (int t = 0; t < 4; ++t) {
        const int cur = t & 1;
        const int nxt = cur ^ 1;
        const int i_loc = w * 4 + t;

        // ---- num_neighbors ----
        unsigned long long ball = __ballot(lvb[cur] >= 1.0f);
        float scale = rsqrtf((float)(__popcll(ball) + 1));

        // ---- pack current x into B-fragments: lane has x[d=32kb+8q+j][n=c4] ----
        F8 bx[2];
        #pragma unroll
        for (int kb = 0; kb < 2; ++kb)
            #pragma unroll
            for (int p = 0; p < 4; ++p)
                bx[kb].u[p] = pk2(xv[cur][kb * 8 + 2 * p], xv[cur][kb * 8 + 2 * p + 1]);

        // ---- issue NEXT iteration's loads now; latency hides under compute.
        //      (LDS_FENCE waits lgkmcnt only -- these stay in flight.) ----
        if (t < 3) {
            #pragma unroll
            for (int kb = 0; kb < 2; ++kb)
                #pragma unroll
                for (int j = 0; j < 8; ++j)
                    xv[nxt][kb * 8 + j] = xb[(t + 1) * 1024 + 512 * kb + 16 * j];
            lvb[nxt] = (lane < 16) ? Lb[(t + 1) * 256] : 0.0f;
        }

        // ---- QKV: 12 MFMAs ----
        f32x4 accQ[2], accK[2], accV[2];
        #pragma unroll
        for (int rh = 0; rh < 2; ++rh) {
            accQ[rh] = __builtin_amdgcn_mfma_f32_16x16x32_bf16(aF[0][rh][0].v, bx[0].v, zz, 0, 0, 0);
            accQ[rh] = __builtin_amdgcn_mfma_f32_16x16x32_bf16(aF[0][rh][1].v, bx[1].v, accQ[rh], 0, 0, 0);
            accK[rh] = __builtin_amdgcn_mfma_f32_16x16x32_bf16(aF[1][rh][0].v, bx[0].v, zz, 0, 0, 0);
            accK[rh] = __builtin_amdgcn_mfma_f32_16x16x32_bf16(aF[1][rh][1].v, bx[1].v, accK[rh], 0, 0, 0);
            accV[rh] = __builtin_amdgcn_mfma_f32_16x16x32_bf16(aF[2][rh][0].v, bx[0].v, zz, 0, 0, 0);
            accV[rh] = __builtin_amdgcn_mfma_f32_16x16x32_bf16(aF[2][rh][1].v, bx[1].v, accV[rh], 0, 0, 0);
        }

        // ---- tanh + stage to LDS (C-frag: row r=4q+reg+16rh, col n=c4).
        //      scale folded into Q staging (same rounding count as before). ----
        #pragma unroll
        for (int rh = 0; rh < 2; ++rh) {
            float tq[4], tk[4], tv[4];
            #pragma unroll
            for (int r2 = 0; r2 < 4; ++r2) {
                tq[r2] = tanh_fast(accQ[rh][r2]);
                tk[r2] = tanh_fast(accK[rh][r2]);
                tv[r2] = tanh_fast(accV[rh][r2]);
            }
            #pragma unroll
            for (int r2 = 0; r2 < 4; ++r2) {
                int r = 4 * q + r2 + 16 * rh;
                qw[r * STR + c4] = bfs(tq[r2] * scale);
                kw[r * STR + c4] = bfs(tk[r2]);
            }
            uint2 vpk; vpk.x = pk2(tv[0], tv[1]); vpk.y = pk2(tv[2], tv[3]);
            *reinterpret_cast<uint2*>(&vtw[c4 * STR + 4 * q + 16 * rh]) = vpk;  // V^T[n=c4][s..s+3]
        }
        LDS_FENCE();   // wave-local: our writes done before our reads below

        // ---- scoresT[s][r] = sum_n K[s][n] Q[r][n]*scale (K-dim n padded) ----
        short8 kfrag[2], qfrag[2];
        #pragma unroll
        for (int hh = 0; hh < 2; ++hh) {
            kfrag[hh] = *reinterpret_cast<const short8*>(&kw[(c4 + 16 * hh) * STR + 8 * q]);
            qfrag[hh] = *reinterpret_cast<const short8*>(&qw[(c4 + 16 * hh) * STR + 8 * q]);
        }
        f32x4 sc[2][2];   // [sh][rh2]: scT[s=4q+reg+16sh][r=c4+16rh2]
        #pragma unroll
        for (int sh = 0; sh < 2; ++sh)
            #pragma unroll
            for (int rh2 = 0; rh2 < 2; ++rh2)
                sc[sh][rh2] = __builtin_amdgcn_mfma_f32_16x16x32_bf16(kfrag[sh], qfrag[rh2], zz, 0, 0, 0);

        // V fragment read now (already fenced; dodges the post-attn fence)
        short8 vfrag = *reinterpret_cast<const short8*>(&vtw[c4 * STR + 8 * q]);

        // ---- softmax over s, NO max pass: |scores| <= 16 so exp is safe ----
        #pragma unroll
        for (int rh2 = 0; rh2 < 2; ++rh2) {
            float v[8];
            float sum = 0.f;
            #pragma unroll
            for (int sh = 0; sh < 2; ++sh)
                #pragma unroll
                for (int r2 = 0; r2 < 4; ++r2) {
                    float e = __expf(sc[sh][rh2][r2]);
                    v[sh * 4 + r2] = e;
                    sum += e;
                }
            sum += __shfl_xor(sum, 16);
            sum += __shfl_xor(sum, 32);
            float inv = __builtin_amdgcn_rcpf(sum);
            #pragma unroll
            for (int sh = 0; sh < 2; ++sh)
                #pragma unroll
                for (int r2 = 0; r2 < 4; ++r2)
                    sc[sh][rh2][r2] = v[sh * 4 + r2] * inv;
        }

        // ---- attn[r][s] to LDS: rows r=c4+16rh2, s = 4q+16sh+{0..3} ----
        #pragma unroll
        for (int rh2 = 0; rh2 < 2; ++rh2)
            #pragma unroll
            for (int sh = 0; sh < 2; ++sh) {
                uint2 ap; ap.x = pk2(sc[sh][rh2][0], sc[sh][rh2][1]);
                ap.y = pk2(sc[sh][rh2][2], sc[sh][rh2][3]);
                *reinterpret_cast<uint2*>(&atw[(c4 + 16 * rh2) * STR + 4 * q + 16 * sh]) = ap;
            }
        LDS_FENCE();

        // ---- PV: o[r][n] = sum_s attn[r][s] V[s][n]  (2 MFMAs, K=s=32) ----
        f32x4 o[2];
        #pragma unroll
        for (int rh = 0; rh < 2; ++rh) {
            short8 afr = *reinterpret_cast<const short8*>(&atw[(c4 + 16 * rh) * STR + 8 * q]);
            o[rh] = __builtin_amdgcn_mfma_f32_16x16x32_bf16(afr, vfrag, zz, 0, 0, 0);
        }

        // ---- R[n] = tanh(sum_r Ao[r] o[r][n]); rows of lane: r = 4q+reg+16rh ----
        float part = 0.f;
        part = fmaf(ao0.x, o[0][0], part); part = fmaf(ao0.y, o[0][1], part);
        part = fmaf(ao0.z, o[0][2], part); part = fmaf(ao0.w, o[0][3], part);
        part = fmaf(ao1.x, o[1][0], part); part = fmaf(ao1.y, o[1][1], part);
        part = fmaf(ao1.z, o[1][2], part); part = fmaf(ao1.w, o[1][3], part);
        part += __shfl_xor(part, 16);
        part += __shfl_xor(part, 32);
        if (lane < 16) {
            float tt = tanh_fast(part);
            sRsq[i_loc * 17 + lane] = tt * tt;
        }
        // NO block barrier here: next iteration only touches this wave's own
        // tiles (in-order LDS per wave handles WAR); sRsq is fenced by the
        // single __syncthreads below.
    }

    __syncthreads();   // the only block-wide barrier: sRsq complete

    // ---- Laplacian-like reconstruction ----
    {
        int i = tid >> 4, j = tid & 15;
        float rij = sRsq[i * 17 + j];
        float srow = 0.0f;
        #pragma unroll
        for (int k = 0; k < 16; ++k) srow += sRsq[i * 17 + k];
        out[(size_t)s_idx * 256 + tid] = (i == j) ? srow : -rij;
    }
}

extern "C" void kernel_launch(void* const* d_in, const int* in_sizes, int n_in,
                              void* d_out, int out_size, void* d_ws, size_t ws_size,
                              hipStream_t stream) {
    const float* x  = (const float*)d_in[0];
    const float* L  = (const float*)d_in[1];
    const float* Aq = (const float*)d_in[2];
    const float* Ak = (const float*)d_in[3];
    const float* Av = (const float*)d_in[4];
    const float* Ao = (const float*)d_in[5];
    float* out = (float*)d_out;

    dim3 grid(S_SAMPLES), block(256);
    hipLaunchKernelGGL(att_mask_kernel, grid, block, 0, stream,
                       x, L, Aq, Ak, Av, Ao, out);
}

// Round 2
// 394.668 us; speedup vs baseline: 1.0124x; 1.0040x over previous
//
#include <hip/hip_runtime.h>
#include <hip/hip_bf16.h>

#define S_SAMPLES 4096
#define NAG 16

typedef __attribute__((ext_vector_type(8))) short short8;   // 8 bf16 = 4 VGPRs (MFMA A/B frag)
typedef __attribute__((ext_vector_type(4))) float f32x4;    // MFMA C/D frag

union F8 { short8 v; unsigned u[4]; };

__device__ __forceinline__ float tanh_fast(float x) {
    float ax = fabsf(x);
    float e  = __expf(-2.0f * ax);
    float t  = (1.0f - e) * __builtin_amdgcn_rcpf(1.0f + e);
    return copysignf(t, x);
}

__device__ __forceinline__ unsigned pk2(float a, float b) {
    float2 f; f.x = a; f.y = b;
    __hip_bfloat162 h = __float22bfloat162_rn(f);
    unsigned r; __builtin_memcpy(&r, &h, 4); return r;
}

__device__ __forceinline__ short bfs(float a) {
    __hip_bfloat16 h = __float2bfloat16(a);
    short r; __builtin_memcpy(&r, &h, 2); return r;
}

__device__ __forceinline__ float4 ld4(const float* p) {
    return *reinterpret_cast<const float4*>(p);
}

// Row stride for all bf16 LDS tiles: 40 shorts = 80 B (16B-multiple for b128).
#define STR 40

// Wave-local LDS fence. All staging tiles are PER-WAVE private, so a block
// barrier is not needed between stage and consume -- only completion of this
// wave's own DS ops. DS ops from one wave are processed in order by the LDS
// pipe; lgkmcnt(0) guarantees the writes have landed before following reads.
// "memory" clobber stops the compiler reordering LDS accesses across it.
#define LDS_FENCE() asm volatile("s_waitcnt lgkmcnt(0)" ::: "memory")

// (256,3): 3 waves/EU min -> 3 blocks/CU = 12 waves/CU. In-flight prefetch
// bytes/CU ~= 12 waves * 4 KB * ~0.65 duty ~= 31 KB > ~22 KB needed to
// saturate 24.6 B/ns/CU at ~800 ns HBM latency. VGPR cap 170: no spill risk
// (aF alone is 48 persistent VGPRs; a 128 cap would force inner-loop spills).
__global__ __launch_bounds__(256, 3) void att_mask_kernel(
    const float* __restrict__ x, const float* __restrict__ L,
    const float* __restrict__ Aq, const float* __restrict__ Ak,
    const float* __restrict__ Av, const float* __restrict__ Ao,
    float* __restrict__ out)
{
    // Per-wave bf16 scratch (no cross-wave sharing except sRsq)
    __shared__ alignas(16) short sQ [4][32 * STR];  // Q[r][n], n zero-padded 16..31
    __shared__ alignas(16) short sK [4][32 * STR];  // K[s][n], zero-padded
    __shared__ alignas(16) short sVt[4][16 * STR];  // V^T[n][s], s=0..31
    __shared__ alignas(16) short sAt[4][32 * STR];  // attn[r][s]
    __shared__ alignas(16) float sRsq[16 * 17];

    const int tid  = threadIdx.x;
    const int lane = tid & 63;
    const int w    = tid >> 6;
    const int c4   = lane & 15;       // n / col index
    const int q    = lane >> 4;       // quad
    const int s_idx = blockIdx.x;

    short* qw = sQ[w];  short* kw = sK[w];  short* vtw = sVt[w];  short* atw = sAt[w];

    // ---- one-time: A-matrix MFMA A-fragments (reg-resident) ----
    // A_frag[m][rh][kb]: lane holds Amat[r = c4+16rh][d = 32kb + 8q + j], j=0..7
    F8 aF[3][2][2];
    {
        const float* mats[3] = { Aq, Ak, Av };
        #pragma unroll
        for (int m = 0; m < 3; ++m)
            #pragma unroll
            for (int rh = 0; rh < 2; ++rh)
                #pragma unroll
                for (int kb = 0; kb < 2; ++kb) {
                    const float* p = mats[m] + (c4 + 16 * rh) * 64 + 32 * kb + 8 * q;
                    float4 a0 = ld4(p), a1 = ld4(p + 4);
                    aF[m][rh][kb].u[0] = pk2(a0.x, a0.y);
                    aF[m][rh][kb].u[1] = pk2(a0.z, a0.w);
                    aF[m][rh][kb].u[2] = pk2(a1.x, a1.y);
                    aF[m][rh][kb].u[3] = pk2(a1.z, a1.w);
                }
    }
    // Ao values matching the o C-fragment rows r = 4q+reg+16rh
    float4 ao0 = ld4(Ao + 4 * q);
    float4 ao1 = ld4(Ao + 16 + 4 * q);

    // ---- zero-fill Q/K pad columns n=16..31 (read by scores MFMA K-dim) ----
    {
        int r = lane & 31, hh = lane >> 5;
        uint2 z; z.x = 0; z.y = 0;
        *reinterpret_cast<uint2*>(&qw[r * STR + 16 + 8 * hh]) = z;
        *reinterpret_cast<uint2*>(&qw[r * STR + 20 + 8 * hh]) = z;
        *reinterpret_cast<uint2*>(&kw[r * STR + 16 + 8 * hh]) = z;
        *reinterpret_cast<uint2*>(&kw[r * STR + 20 + 8 * hh]) = z;
    }

    const f32x4 zz = {0.f, 0.f, 0.f, 0.f};

    // ---- software pipeline: depth-1 prefetch of x rows + L row ----
    const int b0 = s_idx * NAG + w * 4;
    const float* xb = x + (size_t)b0 * 1024 + 128 * q + c4;  // lane's gather base
    const float* Lb = L + (size_t)b0 * 256 + c4;             // row 0 of L[b]

    float xv[2][16];   // ping-pong x fragments (static index via full unroll)
    float lvb[2];

    #pragma unroll
    for (int kb = 0; kb < 2; ++kb)
        #pragma unroll
        for (int j = 0; j < 8; ++j)
            xv[0][kb * 8 + j] = xb[512 * kb + 16 * j];
    lvb[0] = (lane < 16) ? Lb[0] : 0.0f;

    #pragma unroll
    for (int t = 0; t < 4; ++t) {
        const int cur = t & 1;
        const int nxt = cur ^ 1;
        const int i_loc = w * 4 + t;

        // ---- num_neighbors ----
        unsigned long long ball = __ballot(lvb[cur] >= 1.0f);
        float scale = rsqrtf((float)(__popcll(ball) + 1));

        // ---- pack current x into B-fragments: lane has x[d=32kb+8q+j][n=c4] ----
        F8 bx[2];
        #pragma unroll
        for (int kb = 0; kb < 2; ++kb)
            #pragma unroll
            for (int p = 0; p < 4; ++p)
                bx[kb].u[p] = pk2(xv[cur][kb * 8 + 2 * p], xv[cur][kb * 8 + 2 * p + 1]);

        // ---- issue NEXT iteration's loads now; latency hides under compute.
        //      (LDS_FENCE waits lgkmcnt only -- these stay in flight.) ----
        if (t < 3) {
            #pragma unroll
            for (int kb = 0; kb < 2; ++kb)
                #pragma unroll
                for (int j = 0; j < 8; ++j)
                    xv[nxt][kb * 8 + j] = xb[(t + 1) * 1024 + 512 * kb + 16 * j];
            lvb[nxt] = (lane < 16) ? Lb[(t + 1) * 256] : 0.0f;
        }

        // ---- QKV: 12 MFMAs, serialized per matrix to cap acc-reg pressure
        //      at 8 (vs 24 interleaved); tanh work covers MFMA latency. ----
        // Q (scale folded into staging; same rounding count)
        {
            f32x4 a0 = __builtin_amdgcn_mfma_f32_16x16x32_bf16(aF[0][0][0].v, bx[0].v, zz, 0, 0, 0);
            a0 = __builtin_amdgcn_mfma_f32_16x16x32_bf16(aF[0][0][1].v, bx[1].v, a0, 0, 0, 0);
            f32x4 a1 = __builtin_amdgcn_mfma_f32_16x16x32_bf16(aF[0][1][0].v, bx[0].v, zz, 0, 0, 0);
            a1 = __builtin_amdgcn_mfma_f32_16x16x32_bf16(aF[0][1][1].v, bx[1].v, a1, 0, 0, 0);
            #pragma unroll
            for (int r2 = 0; r2 < 4; ++r2) {
                qw[(4 * q + r2) * STR + c4]      = bfs(tanh_fast(a0[r2]) * scale);
                qw[(4 * q + r2 + 16) * STR + c4] = bfs(tanh_fast(a1[r2]) * scale);
            }
        }
        // K
        {
            f32x4 a0 = __builtin_amdgcn_mfma_f32_16x16x32_bf16(aF[1][0][0].v, bx[0].v, zz, 0, 0, 0);
            a0 = __builtin_amdgcn_mfma_f32_16x16x32_bf16(aF[1][0][1].v, bx[1].v, a0, 0, 0, 0);
            f32x4 a1 = __builtin_amdgcn_mfma_f32_16x16x32_bf16(aF[1][1][0].v, bx[0].v, zz, 0, 0, 0);
            a1 = __builtin_amdgcn_mfma_f32_16x16x32_bf16(aF[1][1][1].v, bx[1].v, a1, 0, 0, 0);
            #pragma unroll
            for (int r2 = 0; r2 < 4; ++r2) {
                kw[(4 * q + r2) * STR + c4]      = bfs(tanh_fast(a0[r2]));
                kw[(4 * q + r2 + 16) * STR + c4] = bfs(tanh_fast(a1[r2]));
            }
        }
        // V -> V^T[n][s] for the PV B-fragment
        {
            f32x4 a0 = __builtin_amdgcn_mfma_f32_16x16x32_bf16(aF[2][0][0].v, bx[0].v, zz, 0, 0, 0);
            a0 = __builtin_amdgcn_mfma_f32_16x16x32_bf16(aF[2][0][1].v, bx[1].v, a0, 0, 0, 0);
            f32x4 a1 = __builtin_amdgcn_mfma_f32_16x16x32_bf16(aF[2][1][0].v, bx[0].v, zz, 0, 0, 0);
            a1 = __builtin_amdgcn_mfma_f32_16x16x32_bf16(aF[2][1][1].v, bx[1].v, a1, 0, 0, 0);
            uint2 vpk;
            vpk.x = pk2(tanh_fast(a0[0]), tanh_fast(a0[1]));
            vpk.y = pk2(tanh_fast(a0[2]), tanh_fast(a0[3]));
            *reinterpret_cast<uint2*>(&vtw[c4 * STR + 4 * q]) = vpk;
            vpk.x = pk2(tanh_fast(a1[0]), tanh_fast(a1[1]));
            vpk.y = pk2(tanh_fast(a1[2]), tanh_fast(a1[3]));
            *reinterpret_cast<uint2*>(&vtw[c4 * STR + 4 * q + 16]) = vpk;
        }
        LDS_FENCE();   // wave-local: our writes done before our reads below

        // ---- scoresT[s][r] = sum_n K[s][n] Q[r][n]*scale (K-dim n padded) ----
        short8 kfrag[2], qfrag[2];
        #pragma unroll
        for (int hh = 0; hh < 2; ++hh) {
            kfrag[hh] = *reinterpret_cast<const short8*>(&kw[(c4 + 16 * hh) * STR + 8 * q]);
            qfrag[hh] = *reinterpret_cast<const short8*>(&qw[(c4 + 16 * hh) * STR + 8 * q]);
        }
        f32x4 sc[2][2];   // [sh][rh2]: scT[s=4q+reg+16sh][r=c4+16rh2]
        #pragma unroll
        for (int sh = 0; sh < 2; ++sh)
            #pragma unroll
            for (int rh2 = 0; rh2 < 2; ++rh2)
                sc[sh][rh2] = __builtin_amdgcn_mfma_f32_16x16x32_bf16(kfrag[sh], qfrag[rh2], zz, 0, 0, 0);

        // V fragment read now (already fenced; dodges the post-attn fence)
        short8 vfrag = *reinterpret_cast<const short8*>(&vtw[c4 * STR + 8 * q]);

        // ---- softmax over s, NO max pass: |scores| <= 16 so exp is safe ----
        #pragma unroll
        for (int rh2 = 0; rh2 < 2; ++rh2) {
            float v[8];
            float sum = 0.f;
            #pragma unroll
            for (int sh = 0; sh < 2; ++sh)
                #pragma unroll
                for (int r2 = 0; r2 < 4; ++r2) {
                    float e = __expf(sc[sh][rh2][r2]);
                    v[sh * 4 + r2] = e;
                    sum += e;
                }
            sum += __shfl_xor(sum, 16);
            sum += __shfl_xor(sum, 32);
            float inv = __builtin_amdgcn_rcpf(sum);
            #pragma unroll
            for (int sh = 0; sh < 2; ++sh)
                #pragma unroll
                for (int r2 = 0; r2 < 4; ++r2)
                    sc[sh][rh2][r2] = v[sh * 4 + r2] * inv;
        }

        // ---- attn[r][s] to LDS: rows r=c4+16rh2, s = 4q+16sh+{0..3} ----
        #pragma unroll
        for (int rh2 = 0; rh2 < 2; ++rh2)
            #pragma unroll
            for (int sh = 0; sh < 2; ++sh) {
                uint2 ap; ap.x = pk2(sc[sh][rh2][0], sc[sh][rh2][1]);
                ap.y = pk2(sc[sh][rh2][2], sc[sh][rh2][3]);
                *reinterpret_cast<uint2*>(&atw[(c4 + 16 * rh2) * STR + 4 * q + 16 * sh]) = ap;
            }
        LDS_FENCE();

        // ---- PV: o[r][n] = sum_s attn[r][s] V[s][n]  (2 MFMAs, K=s=32) ----
        f32x4 o[2];
        #pragma unroll
        for (int rh = 0; rh < 2; ++rh) {
            short8 afr = *reinterpret_cast<const short8*>(&atw[(c4 + 16 * rh) * STR + 8 * q]);
            o[rh] = __builtin_amdgcn_mfma_f32_16x16x32_bf16(afr, vfrag, zz, 0, 0, 0);
        }

        // ---- R[n] = tanh(sum_r Ao[r] o[r][n]); rows of lane: r = 4q+reg+16rh ----
        float part = 0.f;
        part = fmaf(ao0.x, o[0][0], part); part = fmaf(ao0.y, o[0][1], part);
        part = fmaf(ao0.z, o[0][2], part); part = fmaf(ao0.w, o[0][3], part);
        part = fmaf(ao1.x, o[1][0], part); part = fmaf(ao1.y, o[1][1], part);
        part = fmaf(ao1.z, o[1][2], part); part = fmaf(ao1.w, o[1][3], part);
        part += __shfl_xor(part, 16);
        part += __shfl_xor(part, 32);
        if (lane < 16) {
            float tt = tanh_fast(part);
            sRsq[i_loc * 17 + lane] = tt * tt;
        }
        // NO block barrier here: next iteration only touches this wave's own
        // tiles (in-order LDS per wave handles WAR); sRsq is fenced by the
        // single __syncthreads below.
    }

    __syncthreads();   // the only block-wide barrier: sRsq complete

    // ---- Laplacian-like reconstruction ----
    {
        int i = tid >> 4, j = tid & 15;
        float rij = sRsq[i * 17 + j];
        float srow = 0.0f;
        #pragma unroll
        for (int k = 0; k < 16; ++k) srow += sRsq[i * 17 + k];
        out[(size_t)s_idx * 256 + tid] = (i == j) ? srow : -rij;
    }
}

extern "C" void kernel_launch(void* const* d_in, const int* in_sizes, int n_in,
                              void* d_out, int out_size, void* d_ws, size_t ws_size,
                              hipStream_t stream) {
    const float* x  = (const float*)d_in[0];
    const float* L  = (const float*)d_in[1];
    const float* Aq = (const float*)d_in[2];
    const float* Ak = (const float*)d_in[3];
    const float* Av = (const float*)d_in[4];
    const float* Ao = (const float*)d_in[5];
    float* out = (float*)d_out;

    dim3 grid(S_SAMPLES), block(256);
    hipLaunchKernelGGL(att_mask_kernel, grid, block, 0, stream,
                       x, L, Aq, Ak, Av, Ao, out);
}